// Round 14
// baseline (89.107 us; speedup 1.0000x reference)
//
#include <hip/hip_runtime.h>
#include <math.h>

// Hausdorff distance, B=16, N=4096, D=3, fp32.
// out[b] = 0.5*(max_gt min_pred d + max_pred min_gt d), d = ||p-q||^2
//
// R14: purge high-latency LDS ops from the tile loop.
// R13's smoking gun: work halved, duration identical (41.5us), all pipes
// <45% busy -> per-tile serialized latency. Mechanism: lgkmcnt is an
// IN-ORDER counter; the per-tile ds_bpermute (__shfl_xor) and LDS
// atomicMin sit in the DS queue ahead of the next tile's bfrag ds_read,
// so every tile pays a full LDS round trip no matter how little
// VALU/MFMA remains.
// Fix: each (wave,half,col) col-min is produced exactly ONCE (cols are
// unique across a wave's tiles) -> plain ds_write_b32 into per-wave-half
// banks scol[8][OPP] (no init, no read-modify, no atomic, no bpermute);
// merge banks after the loop. Col-min chain: 16-deep serial -> depth-5
// tree. Loop body: ds_read_b128 + 2 MFMA + ~47 v_min + ds_write_b32.
//  - fused directions (R13): D = hg + hp - 2g.p via hg,hp in spare K
//    slots; row-min AND col-min from one tile evaluation.
//  - SPLIT=8: OPP=512, TILES=16, LDS 32KB, 2048 blocks.
// C/D (m74/m101, validated R9..R13): col=lane&31,
// row=(reg&3)+8*(reg>>2)+4*(lane>>5).

#define NPTS 4096
#define NB 16
#define TPB 256
#define WAVES 4
#define GPW 64                    // gts per wave (2 MFMA streams)
#define GPB (WAVES * GPW)         // 256 gts per block
#define NGB (NPTS / GPB)          // 16 gt blocks
#define SPLIT 8
#define OPP (NPTS / SPLIT)        // 512 preds staged per block
#define TILES (OPP / 32)          // 16 bfrag tiles per wave

#define WSMIN_N (2 * NB * NPTS)

typedef _Float16 h8 __attribute__((ext_vector_type(8)));
typedef float f16v __attribute__((ext_vector_type(16)));

// min with DPP row_ror:N (VALU pipe; rows of 16 lanes, cyclic rotate)
template <int CTRL>
__device__ __forceinline__ float min_dpp(float v) {
    int s = __builtin_amdgcn_update_dpp(0, __float_as_int(v), CTRL, 0xF, 0xF, true);
    return fminf(v, __int_as_float(s));
}

__global__ __launch_bounds__(TPB) void haus_scan_kernel(
        const float* __restrict__ preds, const float* __restrict__ gts,
        unsigned int* __restrict__ wsmin) {
    const int gt  = blockIdx.x & (NGB - 1);   // gt tile index
    const int sp  = blockIdx.x >> 4;          // pred chunk index (NGB==16)
    const int b   = blockIdx.y;
    const int t   = threadIdx.x;
    const int lane = t & 63, w = t >> 6;
    const int l31 = lane & 31, half = lane >> 5;

    const float* gbp = gts   + (size_t)b * NPTS * 3;   // rows (A side)
    const float* pbp = preds + (size_t)b * NPTS * 3;   // cols (B side)

    __shared__ h8 srec[2 * OPP];              // 16KB: [khalf][point] B records
    __shared__ float scol[8 * OPP];           // 16KB: per (wave,half) col-min banks

    // ---- stage pred chunk: B-form hi/lo records; hp in k9/k10, 1 in k11/k12
#pragma unroll
    for (int i = 0; i < OPP / TPB; ++i) {
        int p = i * TPB + t;
        const float* s = pbp + (size_t)(sp * OPP + p) * 3;
        float x = s[0], y = s[1], z = s[2];
        float hp = fmaf(x, x, fmaf(y, y, z * z));
        _Float16 xh = (_Float16)x, yh = (_Float16)y, zh = (_Float16)z;
        _Float16 xl = (_Float16)(x - (float)xh);
        _Float16 yl = (_Float16)(y - (float)yh);
        _Float16 zl = (_Float16)(z - (float)zh);
        _Float16 hph = (_Float16)hp, hpl = (_Float16)(hp - (float)hph);
        h8 lo, hi;
        lo[0] = xh; lo[1] = yh; lo[2] = zh;       // k0..2: p_hi
        lo[3] = xl; lo[4] = yl; lo[5] = zl;       // k3..5: p_lo
        lo[6] = xh; lo[7] = yh;                   // k6..7: p_hi (x,y)
        hi[0] = zh;                               // k8:    p_hi z
        hi[1] = hph; hi[2] = hpl;                 // k9..10: hp hi/lo
        hi[3] = (_Float16)1; hi[4] = (_Float16)1; // k11..12: 1 (x hg hi/lo)
        hi[5] = (_Float16)0; hi[6] = (_Float16)0; hi[7] = (_Float16)0;
        srec[p] = lo;
        srec[OPP + p] = hi;
    }

    // ---- A-frags: two streams of 32 gts; -2g hi/lo + hg hi/lo in k11/k12
    h8 afrag[2];
#pragma unroll
    for (int a = 0; a < 2; ++a) {
        int m = gt * GPB + w * GPW + a * 32 + l31;
        float gx = gbp[m * 3 + 0], gy = gbp[m * 3 + 1], gz = gbp[m * 3 + 2];
        float hg = fmaf(gx, gx, fmaf(gy, gy, gz * gz));
        _Float16 gxh = (_Float16)gx, gyh = (_Float16)gy, gzh = (_Float16)gz;
        _Float16 gxl = (_Float16)(gx - (float)gxh);
        _Float16 gyl = (_Float16)(gy - (float)gyh);
        _Float16 gzl = (_Float16)(gz - (float)gzh);
        _Float16 hgh = (_Float16)hg, hgl = (_Float16)(hg - (float)hgh);
        const _Float16 n2 = (_Float16)(-2.0f);
        h8 f;
        if (half == 0) {                      // k0..7
            f[0] = n2 * gxh; f[1] = n2 * gyh; f[2] = n2 * gzh;
            f[3] = n2 * gxh; f[4] = n2 * gyh; f[5] = n2 * gzh;
            f[6] = n2 * gxl; f[7] = n2 * gyl;
        } else {                              // k8..15
            f[0] = n2 * gzl;                  // k8
            f[1] = (_Float16)1; f[2] = (_Float16)1;   // k9..10 (x hp hi/lo)
            f[3] = hgh; f[4] = hgl;           // k11..12: hg hi/lo (x 1)
            f[5] = (_Float16)0; f[6] = (_Float16)0; f[7] = (_Float16)0;
        }
        afrag[a] = f;
    }

    f16v zc = {};                             // zero C
    float best0[16], best1[16];
#pragma unroll
    for (int r = 0; r < 16; ++r) { best0[r] = INFINITY; best1[r] = INFINITY; }

    __syncthreads();

    const h8* sptr = srec + half * OPP + l31;
    float* scw = scol + (w * 2 + half) * OPP + l31;   // this lane's col bank
#pragma unroll 4
    for (int tt = 0; tt < TILES; ++tt) {
        h8 bfrag = sptr[tt * 32];             // ds_read_b128, conflict-free
        f16v D0 = __builtin_amdgcn_mfma_f32_32x32x16_f16(afrag[0], bfrag, zc, 0, 0, 0);
        f16v D1 = __builtin_amdgcn_mfma_f32_32x32x16_f16(afrag[1], bfrag, zc, 0, 0, 0);
        // row-min accumulate (rows = gts, fixed per wave)
#pragma unroll
        for (int r = 0; r < 16; ++r) best0[r] = fminf(best0[r], D0[r]);
#pragma unroll
        for (int r = 0; r < 16; ++r) best1[r] = fminf(best1[r], D1[r]);
        // col-min over this lane-half's 32 rows: depth-5 tree (no cross-lane)
        float c8[8];
#pragma unroll
        for (int r = 0; r < 8; ++r)
            c8[r] = fminf(fminf(D0[2 * r], D0[2 * r + 1]),
                          fminf(D1[2 * r], D1[2 * r + 1]));
        float c0 = fminf(fminf(c8[0], c8[1]), fminf(c8[2], c8[3]));
        float c1 = fminf(fminf(c8[4], c8[5]), fminf(c8[6], c8[7]));
        // plain store: each (wave,half,col) is produced exactly once
        scw[tt * 32] = fminf(c0, c1);
    }

    // ---- row epilogue: min over 32 cols (DPP ror + xor16), then atomics
#pragma unroll
    for (int r = 0; r < 16; ++r) {
        float a0 = best0[r], a1 = best1[r];
        a0 = min_dpp<0x121>(a0); a1 = min_dpp<0x121>(a1);   // ror 1
        a0 = min_dpp<0x122>(a0); a1 = min_dpp<0x122>(a1);   // ror 2
        a0 = min_dpp<0x124>(a0); a1 = min_dpp<0x124>(a1);   // ror 4
        a0 = min_dpp<0x128>(a0); a1 = min_dpp<0x128>(a1);   // ror 8
        float s0 = __int_as_float(__builtin_amdgcn_ds_swizzle(__float_as_int(a0), 0x401F));
        float s1 = __int_as_float(__builtin_amdgcn_ds_swizzle(__float_as_int(a1), 0x401F));
        best0[r] = fminf(a0, s0);
        best1[r] = fminf(a1, s1);
    }
    unsigned int* wsrow = wsmin + ((size_t)0 * NB + b) * NPTS + gt * GPB + w * GPW;
    if (l31 == 0) {                           // lanes 0 and 32: disjoint row sets
#pragma unroll
        for (int r = 0; r < 16; ++r) {
            int row = (r & 3) + 8 * (r >> 2) + 4 * half;
            float d0 = fmaxf(best0[r], 0.0f); // D is full d: no hg add
            float d1 = fmaxf(best1[r], 0.0f);
            atomicMin(wsrow + row, __float_as_uint(d0));
            atomicMin(wsrow + 32 + row, __float_as_uint(d1));
        }
    }

    // ---- col merge: 8 banks -> global (plain reads, one atomic per col)
    __syncthreads();
    unsigned int* wscol = wsmin + ((size_t)1 * NB + b) * NPTS + sp * OPP;
#pragma unroll
    for (int i = 0; i < OPP / TPB; ++i) {
        int p = i * TPB + t;
        float m = scol[p];
#pragma unroll
        for (int k = 1; k < 8; ++k) m = fminf(m, scol[k * OPP + p]);
        atomicMin(wscol + p, __float_as_uint(fmaxf(m, 0.0f)));
    }
}

__global__ __launch_bounds__(TPB) void haus_final_kernel(
        const unsigned int* __restrict__ wsmin, float* __restrict__ out) {
    const int b = blockIdx.x;
    const int t = threadIdx.x;
    const float4* w0 = (const float4*)(wsmin + ((size_t)0 * NB + b) * NPTS);
    const float4* w1 = (const float4*)(wsmin + ((size_t)1 * NB + b) * NPTS);
    float m1 = -INFINITY, m2 = -INFINITY;
#pragma unroll
    for (int r = 0; r < NPTS / 4 / TPB; ++r) {   // 4 float4 per thread
        float4 a = w0[r * TPB + t];
        float4 c = w1[r * TPB + t];
        m1 = fmaxf(fmaxf(fmaxf(a.x, a.y), fmaxf(a.z, a.w)), m1);
        m2 = fmaxf(fmaxf(fmaxf(c.x, c.y), fmaxf(c.z, c.w)), m2);
    }
#pragma unroll
    for (int off = 32; off > 0; off >>= 1) {
        m1 = fmaxf(m1, __shfl_down(m1, off, 64));
        m2 = fmaxf(m2, __shfl_down(m2, off, 64));
    }
    __shared__ float s1[4], s2[4];
    if ((t & 63) == 0) { s1[t >> 6] = m1; s2[t >> 6] = m2; }
    __syncthreads();
    if (t == 0) {
        float a = fmaxf(fmaxf(s1[0], s1[1]), fmaxf(s1[2], s1[3]));
        float c = fmaxf(fmaxf(s2[0], s2[1]), fmaxf(s2[2], s2[3]));
        out[b] = 0.5f * (a + c);              // wsmin holds full d both sides
    }
}

extern "C" void kernel_launch(void* const* d_in, const int* in_sizes, int n_in,
                              void* d_out, int out_size, void* d_ws, size_t ws_size,
                              hipStream_t stream) {
    const float* preds = (const float*)d_in[0];
    const float* gts   = (const float*)d_in[1];
    float* out = (float*)d_out;
    unsigned int* wsmin = (unsigned int*)d_ws;   // 512 KB used

    // 0xFF fill = +inf sentinel for uint atomicMin (all finite d bits smaller)
    hipMemsetAsync(wsmin, 0xFF, (size_t)WSMIN_N * sizeof(unsigned int), stream);

    haus_scan_kernel<<<dim3(NGB * SPLIT, NB, 1), dim3(TPB), 0, stream>>>(
        preds, gts, wsmin);

    haus_final_kernel<<<dim3(NB), dim3(TPB), 0, stream>>>(wsmin, out);
}